// Round 1
// baseline (2898.303 us; speedup 1.0000x reference)
//
#include <hip/hip_runtime.h>

typedef unsigned int uint;

#define N_NODES 100000
#define N_EDGES 3200000
#define IN_CH 128
#define HID 64
#define N_GRAPHS 512
#define EPB 4096                                   // edges per block (multisplit)
#define NBLK ((N_EDGES + EPB - 1) / EPB)           // 782
#define GBITS 7
#define GNODES 128                                 // nodes per bucket
#define NB 782                                     // ceil(100000/128)
#define CAP 5120                                   // bucket capacity (mean 4096, 16 sigma)

// ---------------------------------------------------------------------------
// bf16 helpers. NEW layout: row = 32 uints, uint j = (ch j | ch j+32 << 16).
__device__ __forceinline__ uint f2bf1(float f) {
    union { float f; uint i; } v; v.f = f;
    return (v.i + 0x7fffu + ((v.i >> 16) & 1u)) >> 16;    // RNE
}
__device__ __forceinline__ uint pack2(float lo, float hi) {
    return f2bf1(lo) | (f2bf1(hi) << 16);
}
__device__ __forceinline__ float2 ub2(uint u) {
    union { uint i; float f; } a, b;
    a.i = u << 16; b.i = u & 0xffff0000u;
    return make_float2(a.f, b.f);
}

// ---------------------------------------------------------------------------
// One-pass multisplit into 128-node buckets: register-cached edges, LDS
// histogram, one padded global atomic per (bucket, block), scatter.
__global__ __launch_bounds__(256) void scatter_kernel(const int* __restrict__ src,
                                                      const int* __restrict__ dst,
                                                      int* __restrict__ bcnt,
                                                      uint* __restrict__ pairs) {
    __shared__ int h[4 * NB];
    __shared__ int start[NB];
    __shared__ int cur[NB];
    int t = threadIdx.x;
    int base = blockIdx.x * EPB;

    int rs[16], rd[16];
#pragma unroll
    for (int j = 0; j < 16; ++j) {
        int e = base + j * 256 + t;
        if (e < N_EDGES) { rs[j] = src[e]; rd[j] = dst[e]; }
        else rd[j] = -1;
    }
    for (int i = t; i < 4 * NB; i += 256) h[i] = 0;
    __syncthreads();
    int w = t >> 6;
#pragma unroll
    for (int j = 0; j < 16; ++j)
        if (rd[j] >= 0) atomicAdd(&h[w * NB + (rd[j] >> GBITS)], 1);
    __syncthreads();
    for (int b = t; b < NB; b += 256) {
        int tot = h[b] + h[NB + b] + h[2 * NB + b] + h[3 * NB + b];
        start[b] = tot ? atomicAdd(&bcnt[b * 16], tot) : 0;
        cur[b] = 0;
    }
    __syncthreads();
#pragma unroll
    for (int j = 0; j < 16; ++j) {
        if (rd[j] >= 0) {
            int b = rd[j] >> GBITS;
            int r = atomicAdd(&cur[b], 1);
            pairs[(size_t)b * CAP + start[b] + r] =
                ((uint)(rd[j] & (GNODES - 1)) << 24) | (uint)rs[j];   // src < 2^17
        }
    }
}

// ---------------------------------------------------------------------------
// Slim degree pass (replaces CSR build): per-bucket wave-replicated LDS
// histogram -> dis = rsqrt(deg+1). No scan, no second pass, no csr_src.
__global__ __launch_bounds__(256) void degree_kernel(const uint* __restrict__ pairs,
                                                     const int* __restrict__ bcnt,
                                                     float* __restrict__ dis) {
    __shared__ int h4[4 * GNODES];
    int b = blockIdx.x;
    int t = threadIdx.x;
    int w = t >> 6;
    int e0 = b * CAP;
    int e1 = e0 + bcnt[b * 16];

    for (int i = t; i < 4 * GNODES; i += 256) h4[i] = 0;
    __syncthreads();
    int* hw = &h4[w * GNODES];
    int e = e0 + t;
    for (; e + 768 < e1; e += 1024) {
        uint p0 = pairs[e], p1 = pairs[e + 256], p2 = pairs[e + 512], p3 = pairs[e + 768];
        atomicAdd(&hw[p0 >> 24], 1);
        atomicAdd(&hw[p1 >> 24], 1);
        atomicAdd(&hw[p2 >> 24], 1);
        atomicAdd(&hw[p3 >> 24], 1);
    }
    for (; e < e1; e += 256)
        atomicAdd(&hw[pairs[e] >> 24], 1);
    __syncthreads();
    if (t < GNODES) {
        int v = h4[t] + h4[GNODES + t] + h4[2 * GNODES + t] + h4[3 * GNODES + t];
        int n = b * GNODES + t;
        if (n < N_NODES) dis[n] = rsqrtf((float)v + 1.0f);
    }
}

// ---------------------------------------------------------------------------
// GEMM1: Y[M,64](bf16, interleaved j|j+32) = (X[M,128] @ W[128,64]) * dis.
__global__ __launch_bounds__(256) void gemm1_kernel(const float* __restrict__ X,
                                                    const float* __restrict__ W,
                                                    const float* __restrict__ dis,
                                                    uint* __restrict__ Y) {
    __shared__ float Wl[IN_CH * 64];
    __shared__ float Xs[128 * 33];
    int t = threadIdx.x;
    for (int idx = t; idx < IN_CH * 64; idx += 256) Wl[idx] = W[idx];

    int r0 = (t >> 3) * 4;
    int c0 = (t & 7) * 4;                 // channels c0..c0+3 and c0+32..c0+35
    int rowBase = blockIdx.x * 128;

    float acc[4][8];
#pragma unroll
    for (int a = 0; a < 4; ++a)
#pragma unroll
        for (int c = 0; c < 8; ++c) acc[a][c] = 0.f;

    int srow = t >> 1;
    int shh = (t & 1) * 16;
    bool sok = (rowBase + srow) < N_NODES;
    const float* xbase = X + (size_t)(rowBase + srow) * IN_CH + shh;

    float4 nx[4];
#pragma unroll
    for (int f = 0; f < 4; ++f)
        nx[f] = sok ? *reinterpret_cast<const float4*>(xbase + f * 4)
                    : make_float4(0.f, 0.f, 0.f, 0.f);

    for (int kc = 0; kc < IN_CH; kc += 32) {
        if (kc) __syncthreads();
#pragma unroll
        for (int f = 0; f < 4; ++f) {
            int o = srow * 33 + shh + f * 4;
            Xs[o] = nx[f].x; Xs[o + 1] = nx[f].y; Xs[o + 2] = nx[f].z; Xs[o + 3] = nx[f].w;
        }
        __syncthreads();
        if (kc + 32 < IN_CH) {
#pragma unroll
            for (int f = 0; f < 4; ++f)
                nx[f] = sok ? *reinterpret_cast<const float4*>(xbase + kc + 32 + f * 4)
                            : make_float4(0.f, 0.f, 0.f, 0.f);
        }
#pragma unroll
        for (int kk = 0; kk < 32; ++kk) {
            const float4 wa = *reinterpret_cast<const float4*>(&Wl[(kc + kk) * 64 + c0]);
            const float4 wb = *reinterpret_cast<const float4*>(&Wl[(kc + kk) * 64 + c0 + 32]);
            float xr[4];
#pragma unroll
            for (int a = 0; a < 4; ++a) xr[a] = Xs[(r0 + a) * 33 + kk];
#pragma unroll
            for (int a = 0; a < 4; ++a) {
                acc[a][0] += xr[a] * wa.x; acc[a][1] += xr[a] * wa.y;
                acc[a][2] += xr[a] * wa.z; acc[a][3] += xr[a] * wa.w;
                acc[a][4] += xr[a] * wb.x; acc[a][5] += xr[a] * wb.y;
                acc[a][6] += xr[a] * wb.z; acc[a][7] += xr[a] * wb.w;
            }
        }
    }
#pragma unroll
    for (int a = 0; a < 4; ++a) {
        int row = rowBase + r0 + a;
        if (row < N_NODES) {
            float d = dis[row];
            uint4 o;
            o.x = pack2(acc[a][0] * d, acc[a][4] * d);
            o.y = pack2(acc[a][1] * d, acc[a][5] * d);
            o.z = pack2(acc[a][2] * d, acc[a][6] * d);
            o.w = pack2(acc[a][3] * d, acc[a][7] * d);
            *reinterpret_cast<uint4*>(Y + (size_t)row * 32 + (t & 7) * 4) = o;
        }
    }
}

// ---------------------------------------------------------------------------
// GEMM2: Y[M,64](bf16 interleaved) = (relu(X)[M,64] @ W[64,64]) * dis.
// X bf16 interleaved; single-staged (all 64 ch in LDS), one K loop.
__global__ __launch_bounds__(256) void gemm2_kernel(const uint* __restrict__ X,
                                                    const float* __restrict__ W,
                                                    const float* __restrict__ dis,
                                                    uint* __restrict__ Y) {
    __shared__ float Wl[HID * 64];       // 16 KB
    __shared__ float Xs[128 * 65];       // 33.3 KB
    int t = threadIdx.x;
    for (int idx = t; idx < HID * 64; idx += 256) Wl[idx] = W[idx];

    int r0 = (t >> 3) * 4;
    int c0 = (t & 7) * 4;
    int rowBase = blockIdx.x * 128;

    {   // stage: thread (srow, half) unpacks uints half*16..+15 -> ch c and c+32
        int srow = t >> 1, half = t & 1;
        bool sok = (rowBase + srow) < N_NODES;
        float* xs = &Xs[srow * 65 + half * 16];
        if (sok) {
            const uint* xb = X + (size_t)(rowBase + srow) * 32 + half * 16;
            uint4 u0 = *reinterpret_cast<const uint4*>(xb);
            uint4 u1 = *reinterpret_cast<const uint4*>(xb + 4);
            uint4 u2 = *reinterpret_cast<const uint4*>(xb + 8);
            uint4 u3 = *reinterpret_cast<const uint4*>(xb + 12);
            uint us[16] = {u0.x, u0.y, u0.z, u0.w, u1.x, u1.y, u1.z, u1.w,
                           u2.x, u2.y, u2.z, u2.w, u3.x, u3.y, u3.z, u3.w};
#pragma unroll
            for (int k = 0; k < 16; ++k) {
                float2 f = ub2(us[k]);
                xs[k]      = fmaxf(f.x, 0.f);
                xs[32 + k] = fmaxf(f.y, 0.f);
            }
        } else {
#pragma unroll
            for (int k = 0; k < 16; ++k) { xs[k] = 0.f; xs[32 + k] = 0.f; }
        }
    }
    __syncthreads();

    float acc[4][8];
#pragma unroll
    for (int a = 0; a < 4; ++a)
#pragma unroll
        for (int c = 0; c < 8; ++c) acc[a][c] = 0.f;

#pragma unroll 4
    for (int kk = 0; kk < HID; ++kk) {
        const float4 wa = *reinterpret_cast<const float4*>(&Wl[kk * 64 + c0]);
        const float4 wb = *reinterpret_cast<const float4*>(&Wl[kk * 64 + c0 + 32]);
        float xr[4];
#pragma unroll
        for (int a = 0; a < 4; ++a) xr[a] = Xs[(r0 + a) * 65 + kk];
#pragma unroll
        for (int a = 0; a < 4; ++a) {
            acc[a][0] += xr[a] * wa.x; acc[a][1] += xr[a] * wa.y;
            acc[a][2] += xr[a] * wa.z; acc[a][3] += xr[a] * wa.w;
            acc[a][4] += xr[a] * wb.x; acc[a][5] += xr[a] * wb.y;
            acc[a][6] += xr[a] * wb.z; acc[a][7] += xr[a] * wb.w;
        }
    }
#pragma unroll
    for (int a = 0; a < 4; ++a) {
        int row = rowBase + r0 + a;
        if (row < N_NODES) {
            float d = dis[row];
            uint4 o;
            o.x = pack2(acc[a][0] * d, acc[a][4] * d);
            o.y = pack2(acc[a][1] * d, acc[a][5] * d);
            o.z = pack2(acc[a][2] * d, acc[a][6] * d);
            o.w = pack2(acc[a][3] * d, acc[a][7] * d);
            *reinterpret_cast<uint4*>(Y + (size_t)row * 32 + (t & 7) * 4) = o;
        }
    }
}

// ---------------------------------------------------------------------------
// Bucket gather: one block per 128-node bucket, LDS f32 accumulator [128][64].
// 32 lanes/edge (one dword = 2 ch each), ds_add_f32 on bank = lane&31 (2-way,
// free). Init = self term A[n]; epilogue = bias + dis * acc -> bf16 B.
__global__ __launch_bounds__(512) void gather_kernel(const uint* __restrict__ pairs,
                                                     const int* __restrict__ bcnt,
                                                     const float* __restrict__ dis,
                                                     const float* __restrict__ bias,
                                                     const uint* __restrict__ A,
                                                     uint* __restrict__ B) {
    __shared__ float acc[GNODES * 64];   // 32 KB
    int b = blockIdx.x;
    int t = threadIdx.x;
    int e0 = b * CAP;
    int e1 = e0 + bcnt[b * 16];

    {   // init with self term (A already includes dis[n] scale)
        int n = t >> 2, s4 = (t & 3) * 8;
        int gn = b * GNODES + n;
        float* ar = acc + n * 64 + s4;
        if (gn < N_NODES) {
            const uint* ab = A + (size_t)gn * 32 + s4;
            uint4 u0 = *reinterpret_cast<const uint4*>(ab);
            uint4 u1 = *reinterpret_cast<const uint4*>(ab + 4);
            uint us[8] = {u0.x, u0.y, u0.z, u0.w, u1.x, u1.y, u1.z, u1.w};
#pragma unroll
            for (int k = 0; k < 8; ++k) {
                float2 f = ub2(us[k]);
                ar[k] = f.x; ar[32 + k] = f.y;
            }
        } else {
#pragma unroll
            for (int k = 0; k < 8; ++k) { ar[k] = 0.f; ar[32 + k] = 0.f; }
        }
    }
    __syncthreads();

    int hw = t >> 5;            // half-wave id 0..15 (one edge stream each)
    int c = t & 31;             // uint lane within row -> channels c, c+32
    int idx = e0 + hw;
    for (; idx + 48 < e1; idx += 64) {
        uint p0 = pairs[idx];
        uint p1 = pairs[idx + 16];
        uint p2 = pairs[idx + 32];
        uint p3 = pairs[idx + 48];
        uint u0 = A[(size_t)(p0 & 0xFFFFFFu) * 32 + c];
        uint u1 = A[(size_t)(p1 & 0xFFFFFFu) * 32 + c];
        uint u2 = A[(size_t)(p2 & 0xFFFFFFu) * 32 + c];
        uint u3 = A[(size_t)(p3 & 0xFFFFFFu) * 32 + c];
        float* a0 = acc + (p0 >> 24) * 64 + c;
        float* a1 = acc + (p1 >> 24) * 64 + c;
        float* a2 = acc + (p2 >> 24) * 64 + c;
        float* a3 = acc + (p3 >> 24) * 64 + c;
        float2 f0 = ub2(u0), f1 = ub2(u1), f2 = ub2(u2), f3 = ub2(u3);
        atomicAdd(a0, f0.x); atomicAdd(a0 + 32, f0.y);
        atomicAdd(a1, f1.x); atomicAdd(a1 + 32, f1.y);
        atomicAdd(a2, f2.x); atomicAdd(a2 + 32, f2.y);
        atomicAdd(a3, f3.x); atomicAdd(a3 + 32, f3.y);
    }
    for (; idx < e1; idx += 16) {
        uint p = pairs[idx];
        uint u = A[(size_t)(p & 0xFFFFFFu) * 32 + c];
        float* a = acc + (p >> 24) * 64 + c;
        float2 f = ub2(u);
        atomicAdd(a, f.x); atomicAdd(a + 32, f.y);
    }
    __syncthreads();

    {   // epilogue: B[n] = bf16(bias + dis[n] * acc[n])
        int n = t >> 2, s4 = (t & 3) * 8;
        int gn = b * GNODES + n;
        if (gn < N_NODES) {
            float dv = dis[gn];
            const float* ar = acc + n * 64 + s4;
            uint o[8];
#pragma unroll
            for (int k = 0; k < 8; ++k)
                o[k] = pack2(bias[s4 + k] + dv * ar[k],
                             bias[32 + s4 + k] + dv * ar[32 + k]);
            uint4* bp = reinterpret_cast<uint4*>(B + (size_t)gn * 32 + s4);
            bp[0] = make_uint4(o[0], o[1], o[2], o[3]);
            bp[1] = make_uint4(o[4], o[5], o[6], o[7]);
        }
    }
}

// ---------------------------------------------------------------------------
// pool over bf16 B (interleaved ch l, l+32): run-length accumulate per
// half-wave (16 nodes; 32 lanes x 2 ch), relu fused.
__global__ __launch_bounds__(256) void pool_kernel(const uint* __restrict__ B,
                                                   const int* __restrict__ batch,
                                                   float* __restrict__ sums,
                                                   float* __restrict__ cnt) {
    int w = blockIdx.x * 4 + (threadIdx.x >> 6);
    int half = (threadIdx.x >> 5) & 1;
    int l = threadIdx.x & 31;           // uint index -> channels l, l+32
    int n0 = w * 32 + half * 16;
    if (n0 >= N_NODES) return;
    int n1 = min(n0 + 16, N_NODES);
    int curg = batch[n0];
    float a0 = 0.f, a1 = 0.f;
    int run = 0;
    for (int n = n0; n < n1; ++n) {
        int g = batch[n];
        if (g != curg) {
            atomicAdd(&sums[curg * 64 + l], a0);
            atomicAdd(&sums[curg * 64 + 32 + l], a1);
            if (l == 0) atomicAdd(&cnt[curg], (float)run);
            curg = g; a0 = 0.f; a1 = 0.f; run = 0;
        }
        float2 f = ub2(B[(size_t)n * 32 + l]);
        a0 += fmaxf(f.x, 0.f);
        a1 += fmaxf(f.y, 0.f);
        run++;
    }
    atomicAdd(&sums[curg * 64 + l], a0);
    atomicAdd(&sums[curg * 64 + 32 + l], a1);
    if (l == 0) atomicAdd(&cnt[curg], (float)run);
}

__global__ __launch_bounds__(256) void final_kernel(const float* __restrict__ sums,
                                                    const float* __restrict__ cnt,
                                                    float* __restrict__ out) {
    int idx = blockIdx.x * 256 + threadIdx.x;
    if (idx < N_GRAPHS * 64) out[idx] = sums[idx] / fmaxf(cnt[idx >> 6], 1.0f);
}

// ---------------------------------------------------------------------------
extern "C" void kernel_launch(void* const* d_in, const int* in_sizes, int n_in,
                              void* d_out, int out_size, void* d_ws, size_t ws_size,
                              hipStream_t stream) {
    const float* x     = (const float*)d_in[0];
    const int*   edge  = (const int*)d_in[1];   // [2, E]: row0 = src, row1 = dst
    const int*   batch = (const int*)d_in[2];
    const float* W1    = (const float*)d_in[3];
    const float* b1    = (const float*)d_in[4];
    const float* W2    = (const float*)d_in[5];
    const float* b2    = (const float*)d_in[6];
    float* out = (float*)d_out;

    // workspace layout (elements)
    uint*  A     = (uint*)d_ws;                           // 3,200,000 u (bf16 A)
    uint*  B     = A + (size_t)N_NODES * 32;              // 3,200,000 u (bf16 B)
    uint*  pairs = B + (size_t)N_NODES * 32;              // NB*CAP = 4,003,840 u
    float* dis   = (float*)(pairs + (size_t)NB * CAP);    // 100,000 f
    float* sums  = dis + N_NODES;                         // 32,768 f
    float* cnt_f = sums + (size_t)N_GRAPHS * 64;          // 512 f
    int*   bcnt  = (int*)(cnt_f + N_GRAPHS);              // NB*16 = 12,512 i (padded)
    // total ~42 MB

    const int* src = edge;
    const int* dst = edge + N_EDGES;

    // zero sums + cnt + bcnt in one shot (contiguous)
    hipMemsetAsync(sums, 0, (N_GRAPHS * 64 + N_GRAPHS + NB * 16) * sizeof(float), stream);

    // bucket build: multisplit + slim degree pass (no CSR)
    scatter_kernel<<<NBLK, 256, 0, stream>>>(src, dst, bcnt, pairs);
    degree_kernel<<<NB, 256, 0, stream>>>(pairs, bcnt, dis);

    // layer 1: A = bf16((x@W1)*dis) ; B = bf16(b1 + dis*(A[i] + sum A[src]))
    gemm1_kernel<<<(N_NODES + 127) / 128, 256, 0, stream>>>(x, W1, dis, A);
    gather_kernel<<<NB, 512, 0, stream>>>(pairs, bcnt, dis, b1, A, B);

    // layer 2 (relu fused into GEMM2 staging)
    gemm2_kernel<<<(N_NODES + 127) / 128, 256, 0, stream>>>(B, W2, dis, A);
    gather_kernel<<<NB, 512, 0, stream>>>(pairs, bcnt, dis, b2, A, B);

    // pool (relu fused) + finalize
    pool_kernel<<<(N_NODES + 127) / 128, 256, 0, stream>>>(B, batch, sums, cnt_f);
    final_kernel<<<(N_GRAPHS * 64 + 255) / 256, 256, 0, stream>>>(sums, cnt_f, out);
}

// Round 2
// 399.759 us; speedup vs baseline: 7.2501x; 7.2501x over previous
//
#include <hip/hip_runtime.h>

typedef unsigned int uint;
typedef float f32x2 __attribute__((ext_vector_type(2)));

#define N_NODES 100000
#define N_EDGES 3200000
#define IN_CH 128
#define HID 64
#define N_GRAPHS 512
#define EPB 4096                                   // edges per block (binning)
#define NBLK ((N_EDGES + EPB - 1) / EPB)           // 782
#define NB 391                                     // buckets = dst>>8 (256 nodes each)
#define CAP 10240                                  // bucket capacity (mean 8192, 22 sigma)

// ---------------------------------------------------------------------------
// bf16 helpers: A and B matrices are packed bf16 (uint = 2 channels: 2j, 2j+1)
__device__ __forceinline__ uint f2bf1(float f) {
    union { float f; uint i; } v; v.f = f;
    return (v.i + 0x7fffu + ((v.i >> 16) & 1u)) >> 16;    // RNE
}
__device__ __forceinline__ uint pack2(float lo, float hi) {
    return f2bf1(lo) | (f2bf1(hi) << 16);
}
__device__ __forceinline__ float2 ub2(uint u) {
    union { uint i; float f; } a, b;
    a.i = u << 16; b.i = u & 0xffff0000u;
    return make_float2(a.f, b.f);
}
// unpack to ext-vector float2 (v_pk_add_f32-friendly accumulation)
__device__ __forceinline__ f32x2 up2(uint u) {
    union { uint i; float f; } lo, hi;
    lo.i = u << 16; hi.i = u & 0xffff0000u;
    f32x2 r; r.x = lo.f; r.y = hi.f;
    return r;
}

// ---------------------------------------------------------------------------
// One-pass multisplit (R10-proven): edges cached in registers, LDS histogram,
// one padded global atomic per (bucket, block), scatter from registers.
__global__ __launch_bounds__(256) void scatter_kernel(const int* __restrict__ src,
                                                      const int* __restrict__ dst,
                                                      int* __restrict__ bcnt,
                                                      uint* __restrict__ pairs) {
    __shared__ int h[4 * NB];
    __shared__ int start[NB];
    __shared__ int cur[NB];
    int t = threadIdx.x;
    int base = blockIdx.x * EPB;

    int rs[16], rd[16];
#pragma unroll
    for (int j = 0; j < 16; ++j) {
        int e = base + j * 256 + t;
        if (e < N_EDGES) { rs[j] = src[e]; rd[j] = dst[e]; }
        else rd[j] = -1;
    }
    for (int i = t; i < 4 * NB; i += 256) h[i] = 0;
    __syncthreads();
    int w = t >> 6;
#pragma unroll
    for (int j = 0; j < 16; ++j)
        if (rd[j] >= 0) atomicAdd(&h[w * NB + (rd[j] >> 8)], 1);
    __syncthreads();
    for (int b = t; b < NB; b += 256) {
        int tot = h[b] + h[NB + b] + h[2 * NB + b] + h[3 * NB + b];
        start[b] = tot ? atomicAdd(&bcnt[b * 16], tot) : 0;
        cur[b] = 0;
    }
    __syncthreads();
#pragma unroll
    for (int j = 0; j < 16; ++j) {
        if (rd[j] >= 0) {
            int b = rd[j] >> 8;
            int r = atomicAdd(&cur[b], 1);
            pairs[(size_t)b * CAP + start[b] + r] =
                ((uint)(rd[j] & 255) << 24) | (uint)rs[j];   // src < 2^17
        }
    }
}

// ---------------------------------------------------------------------------
// Per-bucket CSR build (256-node buckets, 512 threads):
// pass 1: 8-way wave-replicated LDS histogram, 4-wide batched loads;
// scan -> rstart/rend/dis; pass 2: 4-wide batched cursor fill of csr_src.
__global__ __launch_bounds__(512) void bucket_csr_kernel(const uint* __restrict__ pairs,
                                                         const int* __restrict__ bcnt,
                                                         int* __restrict__ csr_src,
                                                         int* __restrict__ rstart,
                                                         int* __restrict__ rend,
                                                         float* __restrict__ dis) {
    __shared__ int h8[8 * 256];         // replicated histograms (8 KB)
    __shared__ int h[256];              // combined / scan / cursor
    int b = blockIdx.x;
    int t = threadIdx.x;
    int w = t >> 6;                     // wave 0..7
    int e0 = b * CAP;
    int e1 = e0 + bcnt[b * 16];

    for (int i = t; i < 8 * 256; i += 512) h8[i] = 0;
    __syncthreads();

    int* hw = &h8[w * 256];
    int e = e0 + t;
    for (; e + 1536 < e1; e += 2048) {
        uint p0 = pairs[e], p1 = pairs[e + 512], p2 = pairs[e + 1024], p3 = pairs[e + 1536];
        atomicAdd(&hw[p0 >> 24], 1);
        atomicAdd(&hw[p1 >> 24], 1);
        atomicAdd(&hw[p2 >> 24], 1);
        atomicAdd(&hw[p3 >> 24], 1);
    }
    for (; e < e1; e += 512)
        atomicAdd(&hw[pairs[e] >> 24], 1);
    __syncthreads();

    int v = 0;
    if (t < 256) {
#pragma unroll
        for (int j = 0; j < 8; ++j) v += h8[j * 256 + t];
        h[t] = v;
    }
    __syncthreads();
    // inclusive scan of h[256]
#pragma unroll
    for (int o = 1; o < 256; o <<= 1) {
        int x = (t >= o && t < 256) ? h[t - o] : 0;
        __syncthreads();
        if (t < 256) h[t] += x;
        __syncthreads();
    }
    int excl = (t < 256) ? h[t] - v : 0;
    int n = b * 256 + t;
    if (t < 256 && n < N_NODES) {
        rstart[n] = e0 + excl;
        rend[n] = e0 + excl + v;
        dis[n] = rsqrtf((float)v + 1.0f);
    }
    __syncthreads();
    if (t < 256) h[t] = e0 + excl;      // cursor
    __syncthreads();

    e = e0 + t;
    for (; e + 1536 < e1; e += 2048) {
        uint p0 = pairs[e], p1 = pairs[e + 512], p2 = pairs[e + 1024], p3 = pairs[e + 1536];
        int q0 = atomicAdd(&h[p0 >> 24], 1);
        int q1 = atomicAdd(&h[p1 >> 24], 1);
        int q2 = atomicAdd(&h[p2 >> 24], 1);
        int q3 = atomicAdd(&h[p3 >> 24], 1);
        csr_src[q0] = (int)(p0 & 0xFFFFFFu);
        csr_src[q1] = (int)(p1 & 0xFFFFFFu);
        csr_src[q2] = (int)(p2 & 0xFFFFFFu);
        csr_src[q3] = (int)(p3 & 0xFFFFFFu);
    }
    for (; e < e1; e += 512) {
        uint p = pairs[e];
        int pos = atomicAdd(&h[p >> 24], 1);
        csr_src[pos] = (int)(p & 0xFFFFFFu);
    }
}

// ---------------------------------------------------------------------------
// GEMM1: Y[M,64](bf16) = (X[M,128] @ W[128,64]) * dis[row].  X fp32.
// block: 128 rows x 64 ch; thread: 4 rows x 8 ch. Register-prefetch staging.
__global__ __launch_bounds__(256) void gemm1_kernel(const float* __restrict__ X,
                                                    const float* __restrict__ W,
                                                    const float* __restrict__ dis,
                                                    uint* __restrict__ Y) {
    __shared__ float Wl[IN_CH * 64];
    __shared__ float Xs[128 * 33];
    int t = threadIdx.x;
    for (int idx = t; idx < IN_CH * 64; idx += 256) Wl[idx] = W[idx];

    int r0 = (t >> 3) * 4;
    int c0 = (t & 7) * 8;
    int rowBase = blockIdx.x * 128;

    float acc[4][8];
#pragma unroll
    for (int a = 0; a < 4; ++a)
#pragma unroll
        for (int c = 0; c < 8; ++c) acc[a][c] = 0.f;

    int srow = t >> 1;
    int shh = (t & 1) * 16;
    bool sok = (rowBase + srow) < N_NODES;
    const float* xbase = X + (size_t)(rowBase + srow) * IN_CH + shh;

    float4 nx[4];
#pragma unroll
    for (int f = 0; f < 4; ++f)
        nx[f] = sok ? *reinterpret_cast<const float4*>(xbase + f * 4)
                    : make_float4(0.f, 0.f, 0.f, 0.f);

    for (int kc = 0; kc < IN_CH; kc += 32) {
        if (kc) __syncthreads();
#pragma unroll
        for (int f = 0; f < 4; ++f) {
            int o = srow * 33 + shh + f * 4;
            Xs[o] = nx[f].x; Xs[o + 1] = nx[f].y; Xs[o + 2] = nx[f].z; Xs[o + 3] = nx[f].w;
        }
        __syncthreads();
        if (kc + 32 < IN_CH) {
#pragma unroll
            for (int f = 0; f < 4; ++f)
                nx[f] = sok ? *reinterpret_cast<const float4*>(xbase + kc + 32 + f * 4)
                            : make_float4(0.f, 0.f, 0.f, 0.f);
        }
#pragma unroll
        for (int kk = 0; kk < 32; ++kk) {
            const float4 wa = *reinterpret_cast<const float4*>(&Wl[(kc + kk) * 64 + c0]);
            const float4 wb = *reinterpret_cast<const float4*>(&Wl[(kc + kk) * 64 + c0 + 4]);
            float xr[4];
#pragma unroll
            for (int a = 0; a < 4; ++a) xr[a] = Xs[(r0 + a) * 33 + kk];
#pragma unroll
            for (int a = 0; a < 4; ++a) {
                acc[a][0] += xr[a] * wa.x; acc[a][1] += xr[a] * wa.y;
                acc[a][2] += xr[a] * wa.z; acc[a][3] += xr[a] * wa.w;
                acc[a][4] += xr[a] * wb.x; acc[a][5] += xr[a] * wb.y;
                acc[a][6] += xr[a] * wb.z; acc[a][7] += xr[a] * wb.w;
            }
        }
    }
#pragma unroll
    for (int a = 0; a < 4; ++a) {
        int row = rowBase + r0 + a;
        if (row < N_NODES) {
            float d = dis[row];
            uint4 o;
            o.x = pack2(acc[a][0] * d, acc[a][1] * d);
            o.y = pack2(acc[a][2] * d, acc[a][3] * d);
            o.z = pack2(acc[a][4] * d, acc[a][5] * d);
            o.w = pack2(acc[a][6] * d, acc[a][7] * d);
            *reinterpret_cast<uint4*>(Y + (size_t)row * 32 + (t & 7) * 4) = o;
        }
    }
}

// ---------------------------------------------------------------------------
// GEMM2: Y[M,64](bf16) = (relu(X)[M,64] @ W[64,64]) * dis[row].  X bf16 packed.
__global__ __launch_bounds__(256) void gemm2_kernel(const uint* __restrict__ X,
                                                    const float* __restrict__ W,
                                                    const float* __restrict__ dis,
                                                    uint* __restrict__ Y) {
    __shared__ float Wl[HID * 64];
    __shared__ float Xs[128 * 33];
    int t = threadIdx.x;
    for (int idx = t; idx < HID * 64; idx += 256) Wl[idx] = W[idx];

    int r0 = (t >> 3) * 4;
    int c0 = (t & 7) * 8;
    int rowBase = blockIdx.x * 128;

    float acc[4][8];
#pragma unroll
    for (int a = 0; a < 4; ++a)
#pragma unroll
        for (int c = 0; c < 8; ++c) acc[a][c] = 0.f;

    int srow = t >> 1;
    int shh = (t & 1) * 16;
    bool sok = (rowBase + srow) < N_NODES;
    const uint* xbase = X + (size_t)(rowBase + srow) * 32 + (t & 1) * 8;

    uint4 n0_ = make_uint4(0, 0, 0, 0), n1_ = n0_;
    if (sok) {
        n0_ = *reinterpret_cast<const uint4*>(xbase);
        n1_ = *reinterpret_cast<const uint4*>(xbase + 4);
    }

    for (int kc = 0; kc < HID; kc += 32) {
        if (kc) __syncthreads();
        {
            uint us[8] = {n0_.x, n0_.y, n0_.z, n0_.w, n1_.x, n1_.y, n1_.z, n1_.w};
            int o = srow * 33 + shh;
#pragma unroll
            for (int j = 0; j < 8; ++j) {
                float2 f = ub2(us[j]);
                Xs[o + 2 * j]     = fmaxf(f.x, 0.f);
                Xs[o + 2 * j + 1] = fmaxf(f.y, 0.f);
            }
        }
        __syncthreads();
        if (kc + 32 < HID && sok) {
            n0_ = *reinterpret_cast<const uint4*>(xbase + 16);
            n1_ = *reinterpret_cast<const uint4*>(xbase + 20);
        }
#pragma unroll
        for (int kk = 0; kk < 32; ++kk) {
            const float4 wa = *reinterpret_cast<const float4*>(&Wl[(kc + kk) * 64 + c0]);
            const float4 wb = *reinterpret_cast<const float4*>(&Wl[(kc + kk) * 64 + c0 + 4]);
            float xr[4];
#pragma unroll
            for (int a = 0; a < 4; ++a) xr[a] = Xs[(r0 + a) * 33 + kk];
#pragma unroll
            for (int a = 0; a < 4; ++a) {
                acc[a][0] += xr[a] * wa.x; acc[a][1] += xr[a] * wa.y;
                acc[a][2] += xr[a] * wa.z; acc[a][3] += xr[a] * wa.w;
                acc[a][4] += xr[a] * wb.x; acc[a][5] += xr[a] * wb.y;
                acc[a][6] += xr[a] * wb.z; acc[a][7] += xr[a] * wb.w;
            }
        }
    }
#pragma unroll
    for (int a = 0; a < 4; ++a) {
        int row = rowBase + r0 + a;
        if (row < N_NODES) {
            float d = dis[row];
            uint4 o;
            o.x = pack2(acc[a][0] * d, acc[a][1] * d);
            o.y = pack2(acc[a][2] * d, acc[a][3] * d);
            o.z = pack2(acc[a][4] * d, acc[a][5] * d);
            o.w = pack2(acc[a][6] * d, acc[a][7] * d);
            *reinterpret_cast<uint4*>(Y + (size_t)row * 32 + (t & 7) * 4) = o;
        }
    }
}

// ---------------------------------------------------------------------------
// Column-parallel gather: one wave per node; lane&31 OWNS uint-column l
// (channels 2l,2l+1) -> no per-channel cross-lane reduction, no atomics.
// Half-waves split the edge list (4-edge unroll each, stride 8); one
// shfl_xor(32) pair combines halves. Per edge: 1 coalesced 128B row load
// + unpack + v_pk_add_f32.
// B[i] = bf16(bias + dis[i] * (A[i] + sum A[src])),  A = (X@W)*dis  (bf16)
__global__ __launch_bounds__(256) void gather_kernel(const int* __restrict__ rstart,
                                                     const int* __restrict__ rend,
                                                     const int* __restrict__ csr_src,
                                                     const float* __restrict__ dis,
                                                     const float* __restrict__ bias,
                                                     const uint* __restrict__ A,
                                                     uint* __restrict__ B) {
    int i = blockIdx.x * 4 + (threadIdx.x >> 6);
    if (i >= N_NODES) return;
    int lane = threadIdx.x & 63;
    int h = lane >> 5;               // half-wave: splits the edge list
    int l = lane & 31;               // owned uint column (channels 2l, 2l+1)

    f32x2 s0 = (f32x2)0.f, s1 = (f32x2)0.f, s2 = (f32x2)0.f, s3 = (f32x2)0.f;
    if (h == 0)                      // self term (already *dis[i])
        s0 += up2(A[(size_t)i * 32 + l]);

    int end = rend[i];
    int e = rstart[i] + h * 4;
    for (; e + 4 <= end; e += 8) {   // half h covers quads {h*4 + 8k}
        int i0 = csr_src[e];
        int i1 = csr_src[e + 1];
        int i2 = csr_src[e + 2];
        int i3 = csr_src[e + 3];
        uint u0 = A[(size_t)i0 * 32 + l];
        uint u1 = A[(size_t)i1 * 32 + l];
        uint u2 = A[(size_t)i2 * 32 + l];
        uint u3 = A[(size_t)i3 * 32 + l];
        s0 += up2(u0); s1 += up2(u1); s2 += up2(u2); s3 += up2(u3);
    }
    int lim = e + 4;                 // partial quad tail (<=3 edges per half)
    for (; e < end && e < lim; ++e)
        s0 += up2(A[(size_t)csr_src[e] * 32 + l]);

    f32x2 s = (s0 + s1) + (s2 + s3);
    float rx = s.x + __shfl_xor(s.x, 32);
    float ry = s.y + __shfl_xor(s.y, 32);

    if (h == 0) {
        float d = dis[i];
        float2 bv = *reinterpret_cast<const float2*>(&bias[2 * l]);
        B[(size_t)i * 32 + l] = pack2(bv.x + d * rx, bv.y + d * ry);
    }
}

// ---------------------------------------------------------------------------
// pool over bf16 B: batch is sorted -> run-length accumulate per half-wave
// (16 nodes each; 32 lanes x 2 ch cover the 64-ch row), relu fused.
__global__ __launch_bounds__(256) void pool_kernel(const uint* __restrict__ B,
                                                   const int* __restrict__ batch,
                                                   float* __restrict__ sums,
                                                   float* __restrict__ cnt) {
    int w = blockIdx.x * 4 + (threadIdx.x >> 6);
    int half = (threadIdx.x >> 5) & 1;
    int l = threadIdx.x & 31;           // uint index (channels 2l, 2l+1)
    int n0 = w * 32 + half * 16;
    if (n0 >= N_NODES) return;
    int n1 = min(n0 + 16, N_NODES);
    int curg = batch[n0];
    float a0 = 0.f, a1 = 0.f;
    int run = 0;
    for (int n = n0; n < n1; ++n) {
        int g = batch[n];
        if (g != curg) {
            atomicAdd(&sums[curg * 64 + 2 * l], a0);
            atomicAdd(&sums[curg * 64 + 2 * l + 1], a1);
            if (l == 0) atomicAdd(&cnt[curg], (float)run);
            curg = g; a0 = 0.f; a1 = 0.f; run = 0;
        }
        float2 f = ub2(B[(size_t)n * 32 + l]);
        a0 += fmaxf(f.x, 0.f);
        a1 += fmaxf(f.y, 0.f);
        run++;
    }
    atomicAdd(&sums[curg * 64 + 2 * l], a0);
    atomicAdd(&sums[curg * 64 + 2 * l + 1], a1);
    if (l == 0) atomicAdd(&cnt[curg], (float)run);
}

__global__ __launch_bounds__(256) void final_kernel(const float* __restrict__ sums,
                                                    const float* __restrict__ cnt,
                                                    float* __restrict__ out) {
    int idx = blockIdx.x * 256 + threadIdx.x;
    if (idx < N_GRAPHS * 64) out[idx] = sums[idx] / fmaxf(cnt[idx >> 6], 1.0f);
}

// ---------------------------------------------------------------------------
extern "C" void kernel_launch(void* const* d_in, const int* in_sizes, int n_in,
                              void* d_out, int out_size, void* d_ws, size_t ws_size,
                              hipStream_t stream) {
    const float* x     = (const float*)d_in[0];
    const int*   edge  = (const int*)d_in[1];   // [2, E]: row0 = src, row1 = dst
    const int*   batch = (const int*)d_in[2];
    const float* W1    = (const float*)d_in[3];
    const float* b1    = (const float*)d_in[4];
    const float* W2    = (const float*)d_in[5];
    const float* b2    = (const float*)d_in[6];
    float* out = (float*)d_out;

    // workspace layout (elements)
    uint*  A        = (uint*)d_ws;                        // 3,200,000 u (bf16 A)
    uint*  B        = A + (size_t)N_NODES * 32;           // 3,200,000 u (bf16 B)
    uint*  pairs    = B + (size_t)N_NODES * 32;           // NB*CAP = 4,003,840 u
    int*   csr_src  = (int*)(pairs + (size_t)NB * CAP);   // NB*CAP = 4,003,840 i
    float* dis      = (float*)(csr_src + (size_t)NB * CAP); // 100,000 f
    int*   rstart   = (int*)(dis + N_NODES);              // 100,000 i
    int*   rend     = rstart + N_NODES;                   // 100,000 i
    float* sums     = (float*)(rend + N_NODES);           // 32,768 f
    float* cnt_f    = sums + (size_t)N_GRAPHS * 64;       // 512 f
    int*   bcnt     = (int*)(cnt_f + N_GRAPHS);           // NB*16 = 6,256 i (padded)
    // total ~59 MB

    const int* src = edge;
    const int* dst = edge + N_EDGES;

    // zero sums + cnt + bcnt in one shot (contiguous)
    hipMemsetAsync(sums, 0, (N_GRAPHS * 64 + N_GRAPHS + NB * 16) * sizeof(float), stream);

    // CSR build: one-pass multisplit + per-bucket local fill
    scatter_kernel<<<NBLK, 256, 0, stream>>>(src, dst, bcnt, pairs);
    bucket_csr_kernel<<<NB, 512, 0, stream>>>(pairs, bcnt, csr_src, rstart, rend, dis);

    // layer 1: A = bf16((x@W1)*dis) ; B = bf16(b1 + dis*(A[i] + sum A[src]))
    gemm1_kernel<<<(N_NODES + 127) / 128, 256, 0, stream>>>(x, W1, dis, A);
    gather_kernel<<<(N_NODES + 3) / 4, 256, 0, stream>>>(rstart, rend, csr_src, dis, b1, A, B);

    // layer 2 (relu fused into GEMM2 staging)
    gemm2_kernel<<<(N_NODES + 127) / 128, 256, 0, stream>>>(B, W2, dis, A);
    gather_kernel<<<(N_NODES + 3) / 4, 256, 0, stream>>>(rstart, rend, csr_src, dis, b2, A, B);

    // pool (relu fused) + finalize
    pool_kernel<<<(N_NODES + 127) / 128, 256, 0, stream>>>(B, batch, sums, cnt_f);
    final_kernel<<<(N_GRAPHS * 64 + 255) / 256, 256, 0, stream>>>(sums, cnt_f, out);
}

// Round 3
// 372.203 us; speedup vs baseline: 7.7869x; 1.0740x over previous
//
#include <hip/hip_runtime.h>

typedef unsigned int uint;
typedef unsigned short ushort;
typedef float f32x2 __attribute__((ext_vector_type(2)));

#define N_NODES 100000
#define N_EDGES 3200000
#define IN_CH 128
#define HID 64
#define N_GRAPHS 512
#define EPB 4096                                   // edges per block (binning)
#define NBLK ((N_EDGES + EPB - 1) / EPB)           // 782
#define NB 391                                     // buckets = dst>>8 (256 nodes each)
#define CAP 10240                                  // bucket capacity (mean 8192, 22 sigma)

// ---------------------------------------------------------------------------
// bf16 helpers: A and B matrices are packed bf16 (uint = 2 channels: 2j, 2j+1)
__device__ __forceinline__ uint f2bf1(float f) {
    union { float f; uint i; } v; v.f = f;
    return (v.i + 0x7fffu + ((v.i >> 16) & 1u)) >> 16;    // RNE
}
__device__ __forceinline__ uint pack2(float lo, float hi) {
    return f2bf1(lo) | (f2bf1(hi) << 16);
}
__device__ __forceinline__ float2 ub2(uint u) {
    union { uint i; float f; } a, b;
    a.i = u << 16; b.i = u & 0xffff0000u;
    return make_float2(a.f, b.f);
}
// unpack to ext-vector float2 (v_pk_add_f32-friendly accumulation)
__device__ __forceinline__ f32x2 up2(uint u) {
    union { uint i; float f; } lo, hi;
    lo.i = u << 16; hi.i = u & 0xffff0000u;
    f32x2 r; r.x = lo.f; r.y = hi.f;
    return r;
}

// ---------------------------------------------------------------------------
// One-pass multisplit (R10-proven): edges cached in registers, LDS histogram,
// one padded global atomic per (bucket, block), scatter from registers.
__global__ __launch_bounds__(256) void scatter_kernel(const int* __restrict__ src,
                                                      const int* __restrict__ dst,
                                                      int* __restrict__ bcnt,
                                                      uint* __restrict__ pairs) {
    __shared__ int h[4 * NB];
    __shared__ int start[NB];
    __shared__ int cur[NB];
    int t = threadIdx.x;
    int base = blockIdx.x * EPB;

    int rs[16], rd[16];
#pragma unroll
    for (int j = 0; j < 16; ++j) {
        int e = base + j * 256 + t;
        if (e < N_EDGES) { rs[j] = src[e]; rd[j] = dst[e]; }
        else rd[j] = -1;
    }
    for (int i = t; i < 4 * NB; i += 256) h[i] = 0;
    __syncthreads();
    int w = t >> 6;
#pragma unroll
    for (int j = 0; j < 16; ++j)
        if (rd[j] >= 0) atomicAdd(&h[w * NB + (rd[j] >> 8)], 1);
    __syncthreads();
    for (int b = t; b < NB; b += 256) {
        int tot = h[b] + h[NB + b] + h[2 * NB + b] + h[3 * NB + b];
        start[b] = tot ? atomicAdd(&bcnt[b * 16], tot) : 0;
        cur[b] = 0;
    }
    __syncthreads();
#pragma unroll
    for (int j = 0; j < 16; ++j) {
        if (rd[j] >= 0) {
            int b = rd[j] >> 8;
            int r = atomicAdd(&cur[b], 1);
            pairs[(size_t)b * CAP + start[b] + r] =
                ((uint)(rd[j] & 255) << 24) | (uint)rs[j];   // src < 2^17
        }
    }
}

// ---------------------------------------------------------------------------
// Per-bucket CSR build (256-node buckets, 512 threads):
// pass 1: 8-way wave-replicated LDS histogram, 4-wide batched loads;
// scan -> rstart/rend/dis; pass 2: 4-wide batched cursor fill of csr_src.
__global__ __launch_bounds__(512) void bucket_csr_kernel(const uint* __restrict__ pairs,
                                                         const int* __restrict__ bcnt,
                                                         int* __restrict__ csr_src,
                                                         int* __restrict__ rstart,
                                                         int* __restrict__ rend,
                                                         float* __restrict__ dis) {
    __shared__ int h8[8 * 256];         // replicated histograms (8 KB)
    __shared__ int h[256];              // combined / scan / cursor
    int b = blockIdx.x;
    int t = threadIdx.x;
    int w = t >> 6;                     // wave 0..7
    int e0 = b * CAP;
    int e1 = e0 + bcnt[b * 16];

    for (int i = t; i < 8 * 256; i += 512) h8[i] = 0;
    __syncthreads();

    int* hw = &h8[w * 256];
    int e = e0 + t;
    for (; e + 1536 < e1; e += 2048) {
        uint p0 = pairs[e], p1 = pairs[e + 512], p2 = pairs[e + 1024], p3 = pairs[e + 1536];
        atomicAdd(&hw[p0 >> 24], 1);
        atomicAdd(&hw[p1 >> 24], 1);
        atomicAdd(&hw[p2 >> 24], 1);
        atomicAdd(&hw[p3 >> 24], 1);
    }
    for (; e < e1; e += 512)
        atomicAdd(&hw[pairs[e] >> 24], 1);
    __syncthreads();

    int v = 0;
    if (t < 256) {
#pragma unroll
        for (int j = 0; j < 8; ++j) v += h8[j * 256 + t];
        h[t] = v;
    }
    __syncthreads();
    // inclusive scan of h[256]
#pragma unroll
    for (int o = 1; o < 256; o <<= 1) {
        int x = (t >= o && t < 256) ? h[t - o] : 0;
        __syncthreads();
        if (t < 256) h[t] += x;
        __syncthreads();
    }
    int excl = (t < 256) ? h[t] - v : 0;
    int n = b * 256 + t;
    if (t < 256 && n < N_NODES) {
        rstart[n] = e0 + excl;
        rend[n] = e0 + excl + v;
        dis[n] = rsqrtf((float)v + 1.0f);
    }
    __syncthreads();
    if (t < 256) h[t] = e0 + excl;      // cursor
    __syncthreads();

    e = e0 + t;
    for (; e + 1536 < e1; e += 2048) {
        uint p0 = pairs[e], p1 = pairs[e + 512], p2 = pairs[e + 1024], p3 = pairs[e + 1536];
        int q0 = atomicAdd(&h[p0 >> 24], 1);
        int q1 = atomicAdd(&h[p1 >> 24], 1);
        int q2 = atomicAdd(&h[p2 >> 24], 1);
        int q3 = atomicAdd(&h[p3 >> 24], 1);
        csr_src[q0] = (int)(p0 & 0xFFFFFFu);
        csr_src[q1] = (int)(p1 & 0xFFFFFFu);
        csr_src[q2] = (int)(p2 & 0xFFFFFFu);
        csr_src[q3] = (int)(p3 & 0xFFFFFFu);
    }
    for (; e < e1; e += 512) {
        uint p = pairs[e];
        int pos = atomicAdd(&h[p >> 24], 1);
        csr_src[pos] = (int)(p & 0xFFFFFFu);
    }
}

// ---------------------------------------------------------------------------
// GEMM1: Y[M,64](bf16) = (X[M,128] @ W[128,64]) * dis[row].  X fp32.
// block: 128 rows x 64 ch; thread: 4 rows x 8 ch. Register-prefetch staging.
__global__ __launch_bounds__(256) void gemm1_kernel(const float* __restrict__ X,
                                                    const float* __restrict__ W,
                                                    const float* __restrict__ dis,
                                                    uint* __restrict__ Y) {
    __shared__ float Wl[IN_CH * 64];
    __shared__ float Xs[128 * 33];
    int t = threadIdx.x;
    for (int idx = t; idx < IN_CH * 64; idx += 256) Wl[idx] = W[idx];

    int r0 = (t >> 3) * 4;
    int c0 = (t & 7) * 8;
    int rowBase = blockIdx.x * 128;

    float acc[4][8];
#pragma unroll
    for (int a = 0; a < 4; ++a)
#pragma unroll
        for (int c = 0; c < 8; ++c) acc[a][c] = 0.f;

    int srow = t >> 1;
    int shh = (t & 1) * 16;
    bool sok = (rowBase + srow) < N_NODES;
    const float* xbase = X + (size_t)(rowBase + srow) * IN_CH + shh;

    float4 nx[4];
#pragma unroll
    for (int f = 0; f < 4; ++f)
        nx[f] = sok ? *reinterpret_cast<const float4*>(xbase + f * 4)
                    : make_float4(0.f, 0.f, 0.f, 0.f);

    for (int kc = 0; kc < IN_CH; kc += 32) {
        if (kc) __syncthreads();
#pragma unroll
        for (int f = 0; f < 4; ++f) {
            int o = srow * 33 + shh + f * 4;
            Xs[o] = nx[f].x; Xs[o + 1] = nx[f].y; Xs[o + 2] = nx[f].z; Xs[o + 3] = nx[f].w;
        }
        __syncthreads();
        if (kc + 32 < IN_CH) {
#pragma unroll
            for (int f = 0; f < 4; ++f)
                nx[f] = sok ? *reinterpret_cast<const float4*>(xbase + kc + 32 + f * 4)
                            : make_float4(0.f, 0.f, 0.f, 0.f);
        }
#pragma unroll
        for (int kk = 0; kk < 32; ++kk) {
            const float4 wa = *reinterpret_cast<const float4*>(&Wl[(kc + kk) * 64 + c0]);
            const float4 wb = *reinterpret_cast<const float4*>(&Wl[(kc + kk) * 64 + c0 + 4]);
            float xr[4];
#pragma unroll
            for (int a = 0; a < 4; ++a) xr[a] = Xs[(r0 + a) * 33 + kk];
#pragma unroll
            for (int a = 0; a < 4; ++a) {
                acc[a][0] += xr[a] * wa.x; acc[a][1] += xr[a] * wa.y;
                acc[a][2] += xr[a] * wa.z; acc[a][3] += xr[a] * wa.w;
                acc[a][4] += xr[a] * wb.x; acc[a][5] += xr[a] * wb.y;
                acc[a][6] += xr[a] * wb.z; acc[a][7] += xr[a] * wb.w;
            }
        }
    }
#pragma unroll
    for (int a = 0; a < 4; ++a) {
        int row = rowBase + r0 + a;
        if (row < N_NODES) {
            float d = dis[row];
            uint4 o;
            o.x = pack2(acc[a][0] * d, acc[a][1] * d);
            o.y = pack2(acc[a][2] * d, acc[a][3] * d);
            o.z = pack2(acc[a][4] * d, acc[a][5] * d);
            o.w = pack2(acc[a][6] * d, acc[a][7] * d);
            *reinterpret_cast<uint4*>(Y + (size_t)row * 32 + (t & 7) * 4) = o;
        }
    }
}

// ---------------------------------------------------------------------------
// GEMM2: Y[M,64](bf16) = (relu(X)[M,64] @ W[64,64]) * dis[row].  X bf16 packed.
__global__ __launch_bounds__(256) void gemm2_kernel(const uint* __restrict__ X,
                                                    const float* __restrict__ W,
                                                    const float* __restrict__ dis,
                                                    uint* __restrict__ Y) {
    __shared__ float Wl[HID * 64];
    __shared__ float Xs[128 * 33];
    int t = threadIdx.x;
    for (int idx = t; idx < HID * 64; idx += 256) Wl[idx] = W[idx];

    int r0 = (t >> 3) * 4;
    int c0 = (t & 7) * 8;
    int rowBase = blockIdx.x * 128;

    float acc[4][8];
#pragma unroll
    for (int a = 0; a < 4; ++a)
#pragma unroll
        for (int c = 0; c < 8; ++c) acc[a][c] = 0.f;

    int srow = t >> 1;
    int shh = (t & 1) * 16;
    bool sok = (rowBase + srow) < N_NODES;
    const uint* xbase = X + (size_t)(rowBase + srow) * 32 + (t & 1) * 8;

    uint4 n0_ = make_uint4(0, 0, 0, 0), n1_ = n0_;
    if (sok) {
        n0_ = *reinterpret_cast<const uint4*>(xbase);
        n1_ = *reinterpret_cast<const uint4*>(xbase + 4);
    }

    for (int kc = 0; kc < HID; kc += 32) {
        if (kc) __syncthreads();
        {
            uint us[8] = {n0_.x, n0_.y, n0_.z, n0_.w, n1_.x, n1_.y, n1_.z, n1_.w};
            int o = srow * 33 + shh;
#pragma unroll
            for (int j = 0; j < 8; ++j) {
                float2 f = ub2(us[j]);
                Xs[o + 2 * j]     = fmaxf(f.x, 0.f);
                Xs[o + 2 * j + 1] = fmaxf(f.y, 0.f);
            }
        }
        __syncthreads();
        if (kc + 32 < HID && sok) {
            n0_ = *reinterpret_cast<const uint4*>(xbase + 16);
            n1_ = *reinterpret_cast<const uint4*>(xbase + 20);
        }
#pragma unroll
        for (int kk = 0; kk < 32; ++kk) {
            const float4 wa = *reinterpret_cast<const float4*>(&Wl[(kc + kk) * 64 + c0]);
            const float4 wb = *reinterpret_cast<const float4*>(&Wl[(kc + kk) * 64 + c0 + 4]);
            float xr[4];
#pragma unroll
            for (int a = 0; a < 4; ++a) xr[a] = Xs[(r0 + a) * 33 + kk];
#pragma unroll
            for (int a = 0; a < 4; ++a) {
                acc[a][0] += xr[a] * wa.x; acc[a][1] += xr[a] * wa.y;
                acc[a][2] += xr[a] * wa.z; acc[a][3] += xr[a] * wa.w;
                acc[a][4] += xr[a] * wb.x; acc[a][5] += xr[a] * wb.y;
                acc[a][6] += xr[a] * wb.z; acc[a][7] += xr[a] * wb.w;
            }
        }
    }
#pragma unroll
    for (int a = 0; a < 4; ++a) {
        int row = rowBase + r0 + a;
        if (row < N_NODES) {
            float d = dis[row];
            uint4 o;
            o.x = pack2(acc[a][0] * d, acc[a][1] * d);
            o.y = pack2(acc[a][2] * d, acc[a][3] * d);
            o.z = pack2(acc[a][4] * d, acc[a][5] * d);
            o.w = pack2(acc[a][6] * d, acc[a][7] * d);
            *reinterpret_cast<uint4*>(Y + (size_t)row * 32 + (t & 7) * 4) = o;
        }
    }
}

// ---------------------------------------------------------------------------
// wave per node, 8 edges concurrent (8 lanes/edge, bf16x8 = 16B per lane),
// 32-edge unroll (4 uint4 streams = 64B in flight/lane), f32x2 packed accum.
// Epilogue: register-halving butterfly over the 3 q-bits (7 shfl + 7 add);
// each lane ends with ONE channel -> 1 fma + 1 bf16 cvt + 2-byte store
// (64 lanes x 2B = one 128B coalesced store).
// B[i] = bf16(bias + dis[i] * (A[i] + sum A[src])),  A = (X@W)*dis  (bf16)
__global__ __launch_bounds__(256) void gather_kernel(const int* __restrict__ rstart,
                                                     const int* __restrict__ rend,
                                                     const int* __restrict__ csr_src,
                                                     const float* __restrict__ dis,
                                                     const float* __restrict__ bias,
                                                     const uint* __restrict__ A,
                                                     uint* __restrict__ B) {
    int i = blockIdx.x * 4 + (threadIdx.x >> 6);
    if (i >= N_NODES) return;
    int lane = threadIdx.x & 63;
    int q = lane >> 3;               // which of 8 concurrent edges
    int g = lane & 7;                // channel group (channels 8g..8g+7)
    int cu = g * 4;                  // uint4 offset in 32-uint row

    // final owned channel after butterfly: c = 8g + 4*b3 + 2*b4 + b5
    int b3 = (lane >> 3) & 1, b4 = (lane >> 4) & 1, b5 = (lane >> 5) & 1;
    int c = 8 * g + 4 * b3 + 2 * b4 + b5;
    float bi = bias[c];              // hoisted (L1-resident)
    float d = dis[i];

    f32x2 sA[4], sB[4], sC[4], sD[4];
#pragma unroll
    for (int j = 0; j < 4; ++j) {
        sA[j] = (f32x2)0.f; sB[j] = (f32x2)0.f;
        sC[j] = (f32x2)0.f; sD[j] = (f32x2)0.f;
    }

    if (q == 0) {                    // self term (already *dis[i])
        uint4 u = *reinterpret_cast<const uint4*>(&A[(size_t)i * 32 + cu]);
        sA[0] += up2(u.x); sA[1] += up2(u.y); sA[2] += up2(u.z); sA[3] += up2(u.w);
    }

    int e = rstart[i];
    int end = rend[i];
    for (; e + 32 <= end; e += 32) {     // 4 streams: 64B in flight per lane
        int s0 = csr_src[e + q];
        int s1 = csr_src[e + 8 + q];
        int s2 = csr_src[e + 16 + q];
        int s3 = csr_src[e + 24 + q];
        uint4 u0 = *reinterpret_cast<const uint4*>(&A[(size_t)s0 * 32 + cu]);
        uint4 u1 = *reinterpret_cast<const uint4*>(&A[(size_t)s1 * 32 + cu]);
        uint4 u2 = *reinterpret_cast<const uint4*>(&A[(size_t)s2 * 32 + cu]);
        uint4 u3 = *reinterpret_cast<const uint4*>(&A[(size_t)s3 * 32 + cu]);
        sA[0] += up2(u0.x); sA[1] += up2(u0.y); sA[2] += up2(u0.z); sA[3] += up2(u0.w);
        sB[0] += up2(u1.x); sB[1] += up2(u1.y); sB[2] += up2(u1.z); sB[3] += up2(u1.w);
        sC[0] += up2(u2.x); sC[1] += up2(u2.y); sC[2] += up2(u2.z); sC[3] += up2(u2.w);
        sD[0] += up2(u3.x); sD[1] += up2(u3.y); sD[2] += up2(u3.z); sD[3] += up2(u3.w);
    }
    if (e + 16 <= end) {
        int s0 = csr_src[e + q];
        int s1 = csr_src[e + 8 + q];
        uint4 u0 = *reinterpret_cast<const uint4*>(&A[(size_t)s0 * 32 + cu]);
        uint4 u1 = *reinterpret_cast<const uint4*>(&A[(size_t)s1 * 32 + cu]);
        sA[0] += up2(u0.x); sA[1] += up2(u0.y); sA[2] += up2(u0.z); sA[3] += up2(u0.w);
        sB[0] += up2(u1.x); sB[1] += up2(u1.y); sB[2] += up2(u1.z); sB[3] += up2(u1.w);
        e += 16;
    }
    if (e + 8 <= end) {
        int s = csr_src[e + q];
        uint4 u = *reinterpret_cast<const uint4*>(&A[(size_t)s * 32 + cu]);
        sC[0] += up2(u.x); sC[1] += up2(u.y); sC[2] += up2(u.z); sC[3] += up2(u.w);
        e += 8;
    }
    if (e + q < end) {
        int s = csr_src[e + q];
        uint4 u = *reinterpret_cast<const uint4*>(&A[(size_t)s * 32 + cu]);
        sD[0] += up2(u.x); sD[1] += up2(u.y); sD[2] += up2(u.z); sD[3] += up2(u.w);
    }

    float r[8];
#pragma unroll
    for (int j = 0; j < 4; ++j) {
        f32x2 m = (sA[j] + sB[j]) + (sC[j] + sD[j]);
        r[2 * j] = m.x; r[2 * j + 1] = m.y;      // r[j] = channel 8g+j
    }

    // butterfly: reduce over q (lane bits 3,4,5), halving live registers
    float s4[4];
#pragma unroll
    for (int j = 0; j < 4; ++j) {
        float t = b3 ? r[j] : r[j + 4];
        float u = __shfl_xor(t, 8);
        float v = b3 ? r[j + 4] : r[j];
        s4[j] = v + u;               // channel 8g + 4*b3 + j
    }
    float s2[2];
#pragma unroll
    for (int j = 0; j < 2; ++j) {
        float t = b4 ? s4[j] : s4[j + 2];
        float u = __shfl_xor(t, 16);
        float v = b4 ? s4[j + 2] : s4[j];
        s2[j] = v + u;               // channel 8g + 4*b3 + 2*b4 + j
    }
    float t0 = b5 ? s2[0] : s2[1];
    float u0 = __shfl_xor(t0, 32);
    float v0 = b5 ? s2[1] : s2[0];
    float z = v0 + u0;               // channel c

    ((ushort*)B)[(size_t)i * 64 + c] = (ushort)f2bf1(bi + d * z);
}

// ---------------------------------------------------------------------------
// pool over bf16 B: batch is sorted -> run-length accumulate per half-wave
// (16 nodes each; 32 lanes x 2 ch cover the 64-ch row), relu fused.
__global__ __launch_bounds__(256) void pool_kernel(const uint* __restrict__ B,
                                                   const int* __restrict__ batch,
                                                   float* __restrict__ sums,
                                                   float* __restrict__ cnt) {
    int w = blockIdx.x * 4 + (threadIdx.x >> 6);
    int half = (threadIdx.x >> 5) & 1;
    int l = threadIdx.x & 31;           // uint index (channels 2l, 2l+1)
    int n0 = w * 32 + half * 16;
    if (n0 >= N_NODES) return;
    int n1 = min(n0 + 16, N_NODES);
    int curg = batch[n0];
    float a0 = 0.f, a1 = 0.f;
    int run = 0;
    for (int n = n0; n < n1; ++n) {
        int g = batch[n];
        if (g != curg) {
            atomicAdd(&sums[curg * 64 + 2 * l], a0);
            atomicAdd(&sums[curg * 64 + 2 * l + 1], a1);
            if (l == 0) atomicAdd(&cnt[curg], (float)run);
            curg = g; a0 = 0.f; a1 = 0.f; run = 0;
        }
        float2 f = ub2(B[(size_t)n * 32 + l]);
        a0 += fmaxf(f.x, 0.f);
        a1 += fmaxf(f.y, 0.f);
        run++;
    }
    atomicAdd(&sums[curg * 64 + 2 * l], a0);
    atomicAdd(&sums[curg * 64 + 2 * l + 1], a1);
    if (l == 0) atomicAdd(&cnt[curg], (float)run);
}

__global__ __launch_bounds__(256) void final_kernel(const float* __restrict__ sums,
                                                    const float* __restrict__ cnt,
                                                    float* __restrict__ out) {
    int idx = blockIdx.x * 256 + threadIdx.x;
    if (idx < N_GRAPHS * 64) out[idx] = sums[idx] / fmaxf(cnt[idx >> 6], 1.0f);
}

// ---------------------------------------------------------------------------
extern "C" void kernel_launch(void* const* d_in, const int* in_sizes, int n_in,
                              void* d_out, int out_size, void* d_ws, size_t ws_size,
                              hipStream_t stream) {
    const float* x     = (const float*)d_in[0];
    const int*   edge  = (const int*)d_in[1];   // [2, E]: row0 = src, row1 = dst
    const int*   batch = (const int*)d_in[2];
    const float* W1    = (const float*)d_in[3];
    const float* b1    = (const float*)d_in[4];
    const float* W2    = (const float*)d_in[5];
    const float* b2    = (const float*)d_in[6];
    float* out = (float*)d_out;

    // workspace layout (elements)
    uint*  A        = (uint*)d_ws;                        // 3,200,000 u (bf16 A)
    uint*  B        = A + (size_t)N_NODES * 32;           // 3,200,000 u (bf16 B)
    uint*  pairs    = B + (size_t)N_NODES * 32;           // NB*CAP = 4,003,840 u
    int*   csr_src  = (int*)(pairs + (size_t)NB * CAP);   // NB*CAP = 4,003,840 i
    float* dis      = (float*)(csr_src + (size_t)NB * CAP); // 100,000 f
    int*   rstart   = (int*)(dis + N_NODES);              // 100,000 i
    int*   rend     = rstart + N_NODES;                   // 100,000 i
    float* sums     = (float*)(rend + N_NODES);           // 32,768 f
    float* cnt_f    = sums + (size_t)N_GRAPHS * 64;       // 512 f
    int*   bcnt     = (int*)(cnt_f + N_GRAPHS);           // NB*16 = 6,256 i (padded)
    // total ~59 MB

    const int* src = edge;
    const int* dst = edge + N_EDGES;

    // zero sums + cnt + bcnt in one shot (contiguous)
    hipMemsetAsync(sums, 0, (N_GRAPHS * 64 + N_GRAPHS + NB * 16) * sizeof(float), stream);

    // CSR build: one-pass multisplit + per-bucket local fill
    scatter_kernel<<<NBLK, 256, 0, stream>>>(src, dst, bcnt, pairs);
    bucket_csr_kernel<<<NB, 512, 0, stream>>>(pairs, bcnt, csr_src, rstart, rend, dis);

    // layer 1: A = bf16((x@W1)*dis) ; B = bf16(b1 + dis*(A[i] + sum A[src]))
    gemm1_kernel<<<(N_NODES + 127) / 128, 256, 0, stream>>>(x, W1, dis, A);
    gather_kernel<<<(N_NODES + 3) / 4, 256, 0, stream>>>(rstart, rend, csr_src, dis, b1, A, B);

    // layer 2 (relu fused into GEMM2 staging)
    gemm2_kernel<<<(N_NODES + 127) / 128, 256, 0, stream>>>(B, W2, dis, A);
    gather_kernel<<<(N_NODES + 3) / 4, 256, 0, stream>>>(rstart, rend, csr_src, dis, b2, A, B);

    // pool (relu fused) + finalize
    pool_kernel<<<(N_NODES + 127) / 128, 256, 0, stream>>>(B, batch, sums, cnt_f);
    final_kernel<<<(N_GRAPHS * 64 + 255) / 256, 256, 0, stream>>>(sums, cnt_f, out);
}